// Round 1
// baseline (36.750 us; speedup 1.0000x reference)
//
#include <hip/hip_runtime.h>

#define SEQ 1024
#define NPART 4096

// Block-wide sum reduction (wave64 shuffle + LDS across waves).
// Result valid in thread 0.
__device__ __forceinline__ float block_reduce_sum(float v) {
    #pragma unroll
    for (int o = 32; o > 0; o >>= 1) v += __shfl_down(v, o, 64);
    __shared__ float s[16];
    const int lane = threadIdx.x & 63;
    const int w    = threadIdx.x >> 6;
    if (lane == 0) s[w] = v;
    __syncthreads();
    const int nw = blockDim.x >> 6;
    if (w == 0) {
        v = (lane < nw) ? s[lane] : 0.0f;
        #pragma unroll
        for (int o = 8; o > 0; o >>= 1) v += __shfl_down(v, o, 64);
    }
    return v;
}

// One block = 256 threads; each block grid-strides over rows.
// Per row: 256 threads x 4 positions (float4 load), compute circular
// piecewise-cosine target on the fly, accumulate squared diff.
__global__ __launch_bounds__(256) void criterion_partial(
        const float* __restrict__ outputs,
        const int*   __restrict__ indexes,
        float*       __restrict__ part,
        int B) {
    const int tid = threadIdx.x;
    float acc = 0.0f;

    for (int r = blockIdx.x; r < B; r += gridDim.x) {
        // 16B broadcast load of the 4 breakpoints
        const int4 mi = *reinterpret_cast<const int4*>(indexes + (size_t)r * 4);
        int m0 = mi.x, m1 = mi.y, m2 = mi.z, m3 = mi.w;
        // 4-element sorting network (reference sorts; inputs are already
        // sorted, this is 5 cheap min/max pairs of insurance)
        int t;
        if (m0 > m1) { t = m0; m0 = m1; m1 = t; }
        if (m2 > m3) { t = m2; m2 = m3; m3 = t; }
        if (m0 > m2) { t = m0; m0 = m2; m2 = t; }
        if (m1 > m3) { t = m1; m1 = m3; m3 = t; }
        if (m1 > m2) { t = m1; m1 = m2; m2 = t; }

        const float4 v = *reinterpret_cast<const float4*>(
            outputs + (size_t)r * SEQ + tid * 4);
        const float vv[4] = {v.x, v.y, v.z, v.w};
        const int pbase = tid * 4;

        #pragma unroll
        for (int j = 0; j < 4; ++j) {
            const int p = pbase + j;
            // count of breakpoints <= p; 0 means wrap segment (seg=3)
            const int cnt = (p >= m0) + (p >= m1) + (p >= m2) + (p >= m3);
            const int seg = (cnt == 0) ? 3 : (cnt - 1);
            const int start = (seg == 0) ? m0 : (seg == 1) ? m1 : (seg == 2) ? m2 : m3;
            const int nxt   = (seg == 0) ? m1 : (seg == 1) ? m2 : (seg == 2) ? m3 : m0;
            const int n = (nxt - start) & (SEQ - 1);   // circular segment length, >=1
            const int k = (p - start)   & (SEQ - 1);   // offset in segment, < n
            // target = cos(2*pi*k/n)*0.5 + 0.5 ; v_cos_f32 takes revolutions,
            // so feed k/n directly (rev in [0,1))
            const float rev = (float)k * __builtin_amdgcn_rcpf((float)n);
            const float tgt = __builtin_amdgcn_cosf(rev) * 0.5f + 0.5f;
            const float d = vv[j] - tgt;
            acc = fmaf(d, d, acc);
        }
    }

    const float bsum = block_reduce_sum(acc);
    if (threadIdx.x == 0) part[blockIdx.x] = bsum;
}

// Deterministic final reduction: one block sums the NPART partials.
__global__ __launch_bounds__(1024) void criterion_final(
        const float* __restrict__ part,
        float*       __restrict__ out,
        float inv_bn) {
    float v = 0.0f;
    for (int i = threadIdx.x; i < NPART; i += 1024) v += part[i];
    const float s = block_reduce_sum(v);
    if (threadIdx.x == 0) out[0] = s * inv_bn;
}

extern "C" void kernel_launch(void* const* d_in, const int* in_sizes, int n_in,
                              void* d_out, int out_size, void* d_ws, size_t ws_size,
                              hipStream_t stream) {
    const float* outputs = (const float*)d_in[0];   // [B,1,SEQ] f32
    const int*   indexes = (const int*)d_in[1];     // [B,4] i32
    float* out  = (float*)d_out;                    // scalar
    float* part = (float*)d_ws;                     // NPART floats of scratch

    const int total = in_sizes[0];                  // B * SEQ
    const int B = total / SEQ;

    criterion_partial<<<NPART, 256, 0, stream>>>(outputs, indexes, part, B);
    criterion_final<<<1, 1024, 0, stream>>>(part, out, (float)(1.0 / (double)total));
}

// Round 2
// 33.852 us; speedup vs baseline: 1.0856x; 1.0856x over previous
//
#include <hip/hip_runtime.h>

#define SEQ 1024
#define SEQM (SEQ - 1)
#define ROWS_PER_BLOCK 16

// Block-wide sum reduction (wave64 shuffle + LDS across waves). Valid in t0.
__device__ __forceinline__ float block_reduce_sum(float v) {
    #pragma unroll
    for (int o = 32; o > 0; o >>= 1) v += __shfl_down(v, o, 64);
    __shared__ float s[16];
    const int lane = threadIdx.x & 63;
    const int w    = threadIdx.x >> 6;
    if (lane == 0) s[w] = v;
    __syncthreads();
    const int nw = blockDim.x >> 6;
    if (w == 0) {
        v = (lane < nw) ? s[lane] : 0.0f;
        #pragma unroll
        for (int o = 8; o > 0; o >>= 1) v += __shfl_down(v, o, 64);
    }
    return v;
}

// Sort 4 breakpoints (insurance; inputs are already sorted) and precompute
// per-segment reciprocal lengths. Wrap segment: n3 = (m0 - m3) mod 1024.
__device__ __forceinline__ void row_params(int4 mi,
        int& m0, int& m1, int& m2, int& m3,
        float& c0, float& c1, float& c2, float& c3) {
    m0 = mi.x; m1 = mi.y; m2 = mi.z; m3 = mi.w;
    int t;
    if (m0 > m1) { t = m0; m0 = m1; m1 = t; }
    if (m2 > m3) { t = m2; m2 = m3; m3 = t; }
    if (m0 > m2) { t = m0; m0 = m2; m2 = t; }
    if (m1 > m3) { t = m1; m1 = m3; m3 = t; }
    if (m1 > m2) { t = m1; m1 = m2; m2 = t; }
    c0 = __builtin_amdgcn_rcpf((float)((m1 - m0) & SEQM));
    c1 = __builtin_amdgcn_rcpf((float)((m2 - m1) & SEQM));
    c2 = __builtin_amdgcn_rcpf((float)((m3 - m2) & SEQM));
    c3 = __builtin_amdgcn_rcpf((float)((m0 - m3) & SEQM));
}

// start = largest m_i <= p (else m3 for the wrap segment); rc = rcp(seg len).
// Override chain: 4 compares shared by both cndmask chains.
__device__ __forceinline__ float sq_elem(float val, int p,
        int m0, int m1, int m2, int m3,
        float c0, float c1, float c2, float c3, float acc) {
    int start = (p >= m0) ? m0 : m3;
    float rc  = (p >= m0) ? c0 : c3;
    start = (p >= m1) ? m1 : start;  rc = (p >= m1) ? c1 : rc;
    start = (p >= m2) ? m2 : start;  rc = (p >= m2) ? c2 : rc;
    start = (p >= m3) ? m3 : start;  rc = (p >= m3) ? c3 : rc;
    const int k = (p - start) & SEQM;          // offset within segment
    // v_cos_f32 takes revolutions: rev = k/n exactly (no 2*pi round-trip)
    const float tgt = __builtin_amdgcn_cosf((float)k * rc) * 0.5f + 0.5f;
    const float d = val - tgt;
    return fmaf(d, d, acc);
}

// One block = 256 threads owning ROWS_PER_BLOCK contiguous rows.
// 2-row unroll: all 4 loads issued before any dependent compute.
__global__ __launch_bounds__(256) void criterion_partial(
        const float* __restrict__ outputs,
        const int*   __restrict__ indexes,
        float*       __restrict__ part,
        int B) {
    const int tid  = threadIdx.x;
    const int row0 = blockIdx.x * ROWS_PER_BLOCK;
    const int pb   = tid * 4;
    float acc = 0.0f;

    #pragma unroll 1
    for (int rr = 0; rr < ROWS_PER_BLOCK; rr += 2) {
        const int r0 = row0 + rr;
        const int r1 = r0 + 1;
        const int r0c = (r0 < B) ? r0 : (B - 1);
        const int r1c = (r1 < B) ? r1 : (B - 1);
        const float w0 = (r0 < B) ? 1.0f : 0.0f;
        const float w1 = (r1 < B) ? 1.0f : 0.0f;

        const int4   mia = *reinterpret_cast<const int4*>(indexes + (size_t)r0c * 4);
        const int4   mib = *reinterpret_cast<const int4*>(indexes + (size_t)r1c * 4);
        const float4 va  = *reinterpret_cast<const float4*>(outputs + (size_t)r0c * SEQ + pb);
        const float4 vb  = *reinterpret_cast<const float4*>(outputs + (size_t)r1c * SEQ + pb);

        int a0, a1, a2, a3;  float ca0, ca1, ca2, ca3;
        row_params(mia, a0, a1, a2, a3, ca0, ca1, ca2, ca3);
        int b0, b1, b2, b3;  float cb0, cb1, cb2, cb3;
        row_params(mib, b0, b1, b2, b3, cb0, cb1, cb2, cb3);

        float ra = 0.0f, rb = 0.0f;
        ra = sq_elem(va.x, pb + 0, a0, a1, a2, a3, ca0, ca1, ca2, ca3, ra);
        ra = sq_elem(va.y, pb + 1, a0, a1, a2, a3, ca0, ca1, ca2, ca3, ra);
        ra = sq_elem(va.z, pb + 2, a0, a1, a2, a3, ca0, ca1, ca2, ca3, ra);
        ra = sq_elem(va.w, pb + 3, a0, a1, a2, a3, ca0, ca1, ca2, ca3, ra);
        rb = sq_elem(vb.x, pb + 0, b0, b1, b2, b3, cb0, cb1, cb2, cb3, rb);
        rb = sq_elem(vb.y, pb + 1, b0, b1, b2, b3, cb0, cb1, cb2, cb3, rb);
        rb = sq_elem(vb.z, pb + 2, b0, b1, b2, b3, cb0, cb1, cb2, cb3, rb);
        rb = sq_elem(vb.w, pb + 3, b0, b1, b2, b3, cb0, cb1, cb2, cb3, rb);

        acc = fmaf(ra, w0, acc);   // branch-free tail guard (w in {0,1})
        acc = fmaf(rb, w1, acc);
    }

    const float bsum = block_reduce_sum(acc);
    if (tid == 0) part[blockIdx.x] = bsum;
}

// Deterministic final reduction: one block, fixed summation order.
__global__ __launch_bounds__(256) void criterion_final(
        const float* __restrict__ part,
        float*       __restrict__ out,
        int npart, float inv_bn) {
    float v = 0.0f;
    for (int i = threadIdx.x; i < npart; i += 256) v += part[i];
    const float s = block_reduce_sum(v);
    if (threadIdx.x == 0) out[0] = s * inv_bn;
}

extern "C" void kernel_launch(void* const* d_in, const int* in_sizes, int n_in,
                              void* d_out, int out_size, void* d_ws, size_t ws_size,
                              hipStream_t stream) {
    const float* outputs = (const float*)d_in[0];   // [B,1,SEQ] f32
    const int*   indexes = (const int*)d_in[1];     // [B,4] i32
    float* out  = (float*)d_out;                    // scalar
    float* part = (float*)d_ws;                     // npart floats of scratch

    const int total = in_sizes[0];                  // B * SEQ
    const int B = total / SEQ;
    const int npart = (B + ROWS_PER_BLOCK - 1) / ROWS_PER_BLOCK;  // 2048 for B=32768

    criterion_partial<<<npart, 256, 0, stream>>>(outputs, indexes, part, B);
    criterion_final<<<1, 256, 0, stream>>>(part, out, npart,
                                           (float)(1.0 / (double)total));
}

// Round 3
// 30.904 us; speedup vs baseline: 1.1892x; 1.0954x over previous
//
#include <hip/hip_runtime.h>

#define SEQ 1024
#define SEQM (SEQ - 1)
#define ROWS_PER_BLOCK 16

// Block-wide sum reduction (wave64 shuffle + LDS across waves). Valid in t0.
__device__ __forceinline__ float block_reduce_sum(float v) {
    #pragma unroll
    for (int o = 32; o > 0; o >>= 1) v += __shfl_down(v, o, 64);
    __shared__ float s[16];
    const int lane = threadIdx.x & 63;
    const int w    = threadIdx.x >> 6;
    if (lane == 0) s[w] = v;
    __syncthreads();
    const int nw = blockDim.x >> 6;
    if (w == 0) {
        v = (lane < nw) ? s[lane] : 0.0f;
        #pragma unroll
        for (int o = 8; o > 0; o >>= 1) v += __shfl_down(v, o, 64);
    }
    return v;
}

// Per-element target + squared-diff. Params as floats:
//   M = (m0,m1,m2,m3), C = (rcp n0..n3). Default (p < m0) is the wrap
//   segment with start pre-folded: m3 - 1024, so k = pf - start needs no mod.
__device__ __forceinline__ float sq_elem(float val, float pf,
                                         float4 M, float4 C, float acc) {
    float start = M.w - 1024.0f;
    float rc    = C.w;
    start = (pf >= M.x) ? M.x : start;  rc = (pf >= M.x) ? C.x : rc;
    start = (pf >= M.y) ? M.y : start;  rc = (pf >= M.y) ? C.y : rc;
    start = (pf >= M.z) ? M.z : start;  rc = (pf >= M.z) ? C.z : rc;
    start = (pf >= M.w) ? M.w : start;  rc = (pf >= M.w) ? C.w : rc;
    const float rev = (pf - start) * rc;              // k/n in revolutions
    const float tgt = fmaf(__builtin_amdgcn_cosf(rev), 0.5f, 0.5f);
    const float d = val - tgt;
    return fmaf(d, d, acc);
}

__device__ __forceinline__ float row_sq(float4 v, float4 M, float4 C,
                                        float pf0) {
    float r = 0.0f;
    r = sq_elem(v.x, pf0 + 0.0f, M, C, r);
    r = sq_elem(v.y, pf0 + 1.0f, M, C, r);
    r = sq_elem(v.z, pf0 + 2.0f, M, C, r);
    r = sq_elem(v.w, pf0 + 3.0f, M, C, r);
    return r;
}

// One block = 256 threads owning ROWS_PER_BLOCK contiguous rows.
// Stage per-row params (sort + rcp) ONCE per block in LDS, then a 4-row
// unrolled streaming loop: 4 float4 loads in flight, params via broadcast
// ds_read_b128.
__global__ __launch_bounds__(256) void criterion_partial(
        const float* __restrict__ outputs,
        const int*   __restrict__ indexes,
        float*       __restrict__ part,
        int B) {
    __shared__ float4 sM[ROWS_PER_BLOCK];
    __shared__ float4 sC[ROWS_PER_BLOCK];
    __shared__ float  sW[ROWS_PER_BLOCK];

    const int tid  = threadIdx.x;
    const int row0 = blockIdx.x * ROWS_PER_BLOCK;

    if (tid < ROWS_PER_BLOCK) {
        int r = row0 + tid;
        const float w = (r < B) ? 1.0f : 0.0f;
        r = (r < B) ? r : (B - 1);
        const int4 mi = *reinterpret_cast<const int4*>(indexes + (size_t)r * 4);
        int m0 = mi.x, m1 = mi.y, m2 = mi.z, m3 = mi.w;
        int t;  // 4-element sorting network (insurance; inputs arrive sorted)
        if (m0 > m1) { t = m0; m0 = m1; m1 = t; }
        if (m2 > m3) { t = m2; m2 = m3; m3 = t; }
        if (m0 > m2) { t = m0; m0 = m2; m2 = t; }
        if (m1 > m3) { t = m1; m1 = m3; m3 = t; }
        if (m1 > m2) { t = m1; m1 = m2; m2 = t; }
        sM[tid] = make_float4((float)m0, (float)m1, (float)m2, (float)m3);
        sC[tid] = make_float4(
            __builtin_amdgcn_rcpf((float)((m1 - m0) & SEQM)),
            __builtin_amdgcn_rcpf((float)((m2 - m1) & SEQM)),
            __builtin_amdgcn_rcpf((float)((m3 - m2) & SEQM)),
            __builtin_amdgcn_rcpf((float)((m0 - m3) & SEQM)));
        sW[tid] = w;
    }
    __syncthreads();

    const int   pb  = tid * 4;
    const float pf0 = (float)pb;
    float acc = 0.0f;

    #pragma unroll 1
    for (int rr = 0; rr < ROWS_PER_BLOCK; rr += 4) {
        const int r0 = (row0 + rr + 0 < B) ? (row0 + rr + 0) : (B - 1);
        const int r1 = (row0 + rr + 1 < B) ? (row0 + rr + 1) : (B - 1);
        const int r2 = (row0 + rr + 2 < B) ? (row0 + rr + 2) : (B - 1);
        const int r3 = (row0 + rr + 3 < B) ? (row0 + rr + 3) : (B - 1);
        const float4 v0 = *reinterpret_cast<const float4*>(outputs + (size_t)r0 * SEQ + pb);
        const float4 v1 = *reinterpret_cast<const float4*>(outputs + (size_t)r1 * SEQ + pb);
        const float4 v2 = *reinterpret_cast<const float4*>(outputs + (size_t)r2 * SEQ + pb);
        const float4 v3 = *reinterpret_cast<const float4*>(outputs + (size_t)r3 * SEQ + pb);

        acc = fmaf(row_sq(v0, sM[rr + 0], sC[rr + 0], pf0), sW[rr + 0], acc);
        acc = fmaf(row_sq(v1, sM[rr + 1], sC[rr + 1], pf0), sW[rr + 1], acc);
        acc = fmaf(row_sq(v2, sM[rr + 2], sC[rr + 2], pf0), sW[rr + 2], acc);
        acc = fmaf(row_sq(v3, sM[rr + 3], sC[rr + 3], pf0), sW[rr + 3], acc);
    }

    const float bsum = block_reduce_sum(acc);
    if (tid == 0) part[blockIdx.x] = bsum;
}

// Deterministic final reduction: one block, fixed summation order.
__global__ __launch_bounds__(256) void criterion_final(
        const float* __restrict__ part,
        float*       __restrict__ out,
        int npart, float inv_bn) {
    float v = 0.0f;
    for (int i = threadIdx.x; i < npart; i += 256) v += part[i];
    const float s = block_reduce_sum(v);
    if (threadIdx.x == 0) out[0] = s * inv_bn;
}

extern "C" void kernel_launch(void* const* d_in, const int* in_sizes, int n_in,
                              void* d_out, int out_size, void* d_ws, size_t ws_size,
                              hipStream_t stream) {
    const float* outputs = (const float*)d_in[0];   // [B,1,SEQ] f32
    const int*   indexes = (const int*)d_in[1];     // [B,4] i32
    float* out  = (float*)d_out;                    // scalar
    float* part = (float*)d_ws;                     // npart floats of scratch

    const int total = in_sizes[0];                  // B * SEQ
    const int B = total / SEQ;
    const int npart = (B + ROWS_PER_BLOCK - 1) / ROWS_PER_BLOCK;  // 2048

    criterion_partial<<<npart, 256, 0, stream>>>(outputs, indexes, part, B);
    criterion_final<<<1, 256, 0, stream>>>(part, out, npart,
                                           (float)(1.0 / (double)total));
}

// Round 4
// 29.981 us; speedup vs baseline: 1.2258x; 1.0308x over previous
//
#include <hip/hip_runtime.h>

#define SEQ  1024
#define SEQM 1023
#define RPB  16

// Block-wide sum reduction (wave64 shuffle + LDS across waves). Valid in t0.
__device__ __forceinline__ float block_reduce_sum(float v) {
    #pragma unroll
    for (int o = 32; o > 0; o >>= 1) v += __shfl_down(v, o, 64);
    __shared__ float s[16];
    const int lane = threadIdx.x & 63;
    const int w    = threadIdx.x >> 6;
    if (lane == 0) s[w] = v;
    __syncthreads();
    const int nw = blockDim.x >> 6;
    if (w == 0) {
        v = (lane < nw) ? s[lane] : 0.0f;
        #pragma unroll
        for (int o = 8; o > 0; o >>= 1) v += __shfl_down(v, o, 64);
    }
    return v;
}

// Per-element: pick rev = (p - start)/n via rev-candidate selection.
//   rev_i = fma(pf, c_i, -b_i), with rev_i >= 0  <=>  p >= m_i.
//   Default (p < m0) is the wrap candidate fma(pf+1024, c3, -b3).
// Rounding safety: |fma err| <= ulp(m/n) ~ 1.3e-4 << 1/n >= 9.8e-4; at exact
// boundaries cos(0)==cos(1 rev) so either pick is value-identical.
// valm = val - 0.5;  d = fma(cos(rev), -0.5, valm);  acc += d*d.
__device__ __forceinline__ float sq_elem(float valm, float pf, float pfw,
                                         float4 C, float4 Bv, float acc) {
    float rev = fmaf(pfw, C.w, -Bv.w);          // wrap candidate (p < m0)
    const float r0 = fmaf(pf, C.x, -Bv.x);
    const float r1 = fmaf(pf, C.y, -Bv.y);
    const float r2 = fmaf(pf, C.z, -Bv.z);
    const float r3 = fmaf(pf, C.w, -Bv.w);
    rev = (r0 >= 0.0f) ? r0 : rev;
    rev = (r1 >= 0.0f) ? r1 : rev;
    rev = (r2 >= 0.0f) ? r2 : rev;
    rev = (r3 >= 0.0f) ? r3 : rev;
    const float d = fmaf(__builtin_amdgcn_cosf(rev), -0.5f, valm);
    return fmaf(d, d, acc);
}

template <bool WEIGHTED>
__device__ __forceinline__ float do_row(float4 v, float4 C, float4 Bv, float w,
                                        float pf0, float pf1, float pf2, float pf3,
                                        float pw0, float pw1, float pw2, float pw3,
                                        float acc) {
    float r = WEIGHTED ? 0.0f : acc;
    r = sq_elem(v.x - 0.5f, pf0, pw0, C, Bv, r);
    r = sq_elem(v.y - 0.5f, pf1, pw1, C, Bv, r);
    r = sq_elem(v.z - 0.5f, pf2, pw2, C, Bv, r);
    r = sq_elem(v.w - 0.5f, pf3, pw3, C, Bv, r);
    return WEIGHTED ? fmaf(r, w, acc) : r;
}

// One block = 256 threads owning RPB contiguous rows. Stage per-row
// (c_i, b_i) once per block in LDS; stream rows 4 at a time (4 float4
// loads in flight), params via broadcast ds_read_b128.
__global__ __launch_bounds__(256) void criterion_partial(
        const float* __restrict__ outputs,
        const int*   __restrict__ indexes,
        float*       __restrict__ part,
        int B) {
    __shared__ float4 sC[RPB];
    __shared__ float4 sB[RPB];
    __shared__ float  sW[RPB];

    const int tid  = threadIdx.x;
    const int row0 = blockIdx.x * RPB;
    const bool full = (row0 + RPB <= B);

    if (tid < RPB) {
        int r = row0 + tid;
        sW[tid] = (r < B) ? 1.0f : 0.0f;
        r = (r < B) ? r : (B - 1);
        const int4 mi = *reinterpret_cast<const int4*>(indexes + (size_t)r * 4);
        int m0 = mi.x, m1 = mi.y, m2 = mi.z, m3 = mi.w;
        int t;  // 4-element sorting network (insurance; inputs arrive sorted)
        if (m0 > m1) { t = m0; m0 = m1; m1 = t; }
        if (m2 > m3) { t = m2; m2 = m3; m3 = t; }
        if (m0 > m2) { t = m0; m0 = m2; m2 = t; }
        if (m1 > m3) { t = m1; m1 = m3; m3 = t; }
        if (m1 > m2) { t = m1; m1 = m2; m2 = t; }
        const float c0 = __builtin_amdgcn_rcpf((float)((m1 - m0) & SEQM));
        const float c1 = __builtin_amdgcn_rcpf((float)((m2 - m1) & SEQM));
        const float c2 = __builtin_amdgcn_rcpf((float)((m3 - m2) & SEQM));
        const float c3 = __builtin_amdgcn_rcpf((float)((m0 - m3) & SEQM));
        sC[tid] = make_float4(c0, c1, c2, c3);
        sB[tid] = make_float4((float)m0 * c0, (float)m1 * c1,
                              (float)m2 * c2, (float)m3 * c3);
    }
    __syncthreads();

    const int   pb  = tid * 4;
    const float pf0 = (float)pb,        pf1 = pf0 + 1.0f;
    const float pf2 = pf0 + 2.0f,       pf3 = pf0 + 3.0f;
    const float pw0 = pf0 + 1024.0f,    pw1 = pw0 + 1.0f;
    const float pw2 = pw0 + 2.0f,       pw3 = pw0 + 3.0f;
    float acc = 0.0f;

    if (full) {
        const float* rowp = outputs + (size_t)row0 * SEQ + pb;
        #pragma unroll 1
        for (int rr = 0; rr < RPB; rr += 4) {
            const float4 v0 = *reinterpret_cast<const float4*>(rowp + (rr + 0) * SEQ);
            const float4 v1 = *reinterpret_cast<const float4*>(rowp + (rr + 1) * SEQ);
            const float4 v2 = *reinterpret_cast<const float4*>(rowp + (rr + 2) * SEQ);
            const float4 v3 = *reinterpret_cast<const float4*>(rowp + (rr + 3) * SEQ);
            acc = do_row<false>(v0, sC[rr + 0], sB[rr + 0], 1.0f,
                                pf0, pf1, pf2, pf3, pw0, pw1, pw2, pw3, acc);
            acc = do_row<false>(v1, sC[rr + 1], sB[rr + 1], 1.0f,
                                pf0, pf1, pf2, pf3, pw0, pw1, pw2, pw3, acc);
            acc = do_row<false>(v2, sC[rr + 2], sB[rr + 2], 1.0f,
                                pf0, pf1, pf2, pf3, pw0, pw1, pw2, pw3, acc);
            acc = do_row<false>(v3, sC[rr + 3], sB[rr + 3], 1.0f,
                                pf0, pf1, pf2, pf3, pw0, pw1, pw2, pw3, acc);
        }
    } else {
        #pragma unroll 1
        for (int rr = 0; rr < RPB; ++rr) {
            const int r = (row0 + rr < B) ? (row0 + rr) : (B - 1);
            const float4 v = *reinterpret_cast<const float4*>(
                outputs + (size_t)r * SEQ + pb);
            acc = do_row<true>(v, sC[rr], sB[rr], sW[rr],
                               pf0, pf1, pf2, pf3, pw0, pw1, pw2, pw3, acc);
        }
    }

    const float bsum = block_reduce_sum(acc);
    if (tid == 0) part[blockIdx.x] = bsum;
}

// Deterministic final reduction: one block, fixed summation order.
__global__ __launch_bounds__(256) void criterion_final(
        const float* __restrict__ part,
        float*       __restrict__ out,
        int npart, float inv_bn) {
    float v = 0.0f;
    for (int i = threadIdx.x; i < npart; i += 256) v += part[i];
    const float s = block_reduce_sum(v);
    if (threadIdx.x == 0) out[0] = s * inv_bn;
}

extern "C" void kernel_launch(void* const* d_in, const int* in_sizes, int n_in,
                              void* d_out, int out_size, void* d_ws, size_t ws_size,
                              hipStream_t stream) {
    const float* outputs = (const float*)d_in[0];   // [B,1,SEQ] f32
    const int*   indexes = (const int*)d_in[1];     // [B,4] i32
    float* out  = (float*)d_out;                    // scalar
    float* part = (float*)d_ws;                     // npart floats of scratch

    const int total = in_sizes[0];                  // B * SEQ
    const int B = total / SEQ;
    const int npart = (B + RPB - 1) / RPB;          // 2048 for B=32768

    criterion_partial<<<npart, 256, 0, stream>>>(outputs, indexes, part, B);
    criterion_final<<<1, 256, 0, stream>>>(part, out, npart,
                                           (float)(1.0 / (double)total));
}